// Round 14
// baseline (140.202 us; speedup 1.0000x reference)
//
#include <hip/hip_runtime.h>
#include <hip/hip_bf16.h>

#define NTOK 2048
#define DMODEL 768
#define DFF 3072
#define NEXP 8
#define MAXT 40  // max (expert,m0) tiles at M=64: 2048/64 + 7 = 39

typedef short bf16x8 __attribute__((ext_vector_type(8)));
typedef float f32x4 __attribute__((ext_vector_type(4)));

typedef __attribute__((address_space(1))) const char GCHAR;
typedef __attribute__((address_space(3))) char LCHAR;
#define GL16(g, l) __builtin_amdgcn_global_load_lds((GCHAR*)(g), (LCHAR*)(l), 16, 0, 0)

// ---- transpose one 64x64 tile: W[e][K][N] fp32 -> WT[e][N][K] bf16 (smem: 64x65 f32) ----
template <int K, int N>
__device__ void transpose_tile(const float* __restrict__ W, __hip_bfloat16* __restrict__ WT,
                               int e, int k0, int n0, float* T) {
  const int t = threadIdx.x;
  {
    const int kr = t >> 4;
    const int nc = (t & 15) * 4;
    const float* src = W + ((size_t)e * K + k0) * N + n0;
#pragma unroll
    for (int i = 0; i < 4; i++) {
      float4 v = *(const float4*)(src + (size_t)(kr + i * 16) * N + nc);
      T[(kr + i * 16) * 65 + nc + 0] = v.x;
      T[(kr + i * 16) * 65 + nc + 1] = v.y;
      T[(kr + i * 16) * 65 + nc + 2] = v.z;
      T[(kr + i * 16) * 65 + nc + 3] = v.w;
    }
  }
  __syncthreads();
  {
    const int n = t >> 2;
    const int kq = (t & 3) * 16;
    __align__(16) __hip_bfloat16 u[16];
#pragma unroll
    for (int j = 0; j < 16; j++) u[j] = __float2bfloat16(T[(kq + j) * 65 + n]);
    __hip_bfloat16* dst = WT + ((size_t)e * N + n0 + n) * K + k0 + kq;
    *(int4*)dst = *(const int4*)&u[0];
    *(int4*)(dst + 8) = *(const int4*)&u[8];
  }
}

// ---------------- router (blocks <512) fused with w1 transpose (blocks >=512) ----------
__global__ __launch_bounds__(256) void k_router_t1(
    const float* __restrict__ x, const float* __restrict__ rw,
    const float* __restrict__ rb, __hip_bfloat16* __restrict__ xbf,
    int* __restrict__ eidx, int* __restrict__ cnt,
    const float* __restrict__ w1, __hip_bfloat16* __restrict__ wT1) {
  __shared__ float T[64 * 65];
  if (blockIdx.x >= 512) {
    int tb = blockIdx.x - 512;
    int n_i = tb % (DFF / 64);
    int k_i = (tb / (DFF / 64)) % (DMODEL / 64);
    int e = tb / ((DFF / 64) * (DMODEL / 64));
    transpose_tile<DMODEL, DFF>(w1, wT1, e, k_i * 64, n_i * 64, T);
    return;
  }
  int tok = (blockIdx.x * blockDim.x + threadIdx.x) >> 6;
  int lane = threadIdx.x & 63;
  if (tok >= NTOK) return;
  const float* xr = x + (size_t)tok * DMODEL;
  double acc[NEXP];
#pragma unroll
  for (int e = 0; e < NEXP; e++) acc[e] = 0.0;
  for (int d0 = 0; d0 < DMODEL; d0 += 64) {
    float v = xr[d0 + lane];
    xbf[(size_t)tok * DMODEL + d0 + lane] = __float2bfloat16(v);
    const float* wrow = rw + (size_t)(d0 + lane) * NEXP;
#pragma unroll
    for (int e = 0; e < NEXP; e++) acc[e] += (double)v * (double)wrow[e];
  }
#pragma unroll
  for (int e = 0; e < NEXP; e++) {
    double a = acc[e];
#pragma unroll
    for (int s = 32; s > 0; s >>= 1) a += __shfl_xor(a, s);
    acc[e] = a;
  }
  if (lane == 0) {
    int best = 0;
    double bv = acc[0] + (double)rb[0];
#pragma unroll
    for (int e = 1; e < NEXP; e++) {
      double v = acc[e] + (double)rb[e];
      if (v > bv) { bv = v; best = e; }  // strict > keeps first max (jnp.argmax)
    }
    eidx[tok] = best;
    atomicAdd(&cnt[best], 1);
  }
}

// ------- fused: prefix scan + loss + tile list (M=64) + packed token-list build -------
__global__ __launch_bounds__(256) void k_scanbuild(
    const int* __restrict__ cnt, int* __restrict__ off, float* __restrict__ loss,
    int* __restrict__ tiles, int* __restrict__ ntile,
    const int* __restrict__ eidx, int* __restrict__ list) {
  __shared__ int s_cur[NEXP];
  if (threadIdx.x == 0) {
    int s = 0;
    float l = 0.f;
    int nt = 0;
    for (int e = 0; e < NEXP; e++) {
      off[e] = s;
      s_cur[e] = s;
      for (int m = 0; m < cnt[e]; m += 64) tiles[nt++] = (e << 20) | m;
      s += cnt[e];
      float u = (float)cnt[e] / (float)NTOK - 1.0f / (float)NEXP;
      l += u * u;
    }
    *ntile = nt;
    *loss = l / (float)NEXP;
  }
  __syncthreads();
  for (int t = threadIdx.x; t < NTOK; t += 256) {
    int e = eidx[t];
    int p = atomicAdd(&s_cur[e], 1);
    list[p] = t;
  }
}

// ---- grouped GEMM (r13 core): 64Mx128N tile, BK=32, dbuf 24KB LDS (6 blocks/CU),
// counted vmcnt(3) + raw barriers, gload_lds both operands, XCD swizzle,
// fused 64x64 w2-transpose blocks, atomic split-K epilogue (r14: partials dropped).
// Chunk swizzle: phys 16B chunk = log ^ ((row>>1)&3).
template <int K_TOT, int KCHUNK, int N, int NSPLIT, bool RELU_BF16, bool GATHER_A,
          bool ATOMIC_C, int TK, int TN>
__global__ __launch_bounds__(256, 6) void k_gemm9(
    const __hip_bfloat16* __restrict__ A, const __hip_bfloat16* __restrict__ BT,
    const float* __restrict__ bias, void* __restrict__ Cout,
    const int* __restrict__ cnt, const int* __restrict__ off,
    const int* __restrict__ list, const int* __restrict__ tiles,
    const int* __restrict__ ntile, const float* __restrict__ Tsrc,
    __hip_bfloat16* __restrict__ Tdst) {
  constexpr int NX = N / 128;
  constexpr int W = NX * MAXT * NSPLIT;
  constexpr int NT = KCHUNK / 32;
  __shared__ __align__(16) char smem[24576];  // A dbuf 2x4KB @0 | B dbuf 2x8KB @8192
                                              // transpose branch: 64x65 f32 = 16.9KB

  if constexpr (TK > 0) {
    if (blockIdx.x >= W) {
      int tb = blockIdx.x - W;
      int n_i = tb % (TN / 64);
      int k_i = (tb / (TN / 64)) % (TK / 64);
      int e = tb / ((TN / 64) * (TK / 64));
      transpose_tile<TK, TN>(Tsrc, Tdst, e, k_i * 64, n_i * 64, (float*)smem);
      return;
    }
  }

  // bijective XCD swizzle; decompose split-fastest, then tile, then n-tile
  int b = blockIdx.x;
  constexpr int q = W / 8, r = W % 8;
  const int xcd = b & 7, ii = b >> 3;
  const int widx = (xcd < r ? xcd * (q + 1) : r * (q + 1) + (xcd - r) * q) + ii;
  const int split = widx % NSPLIT;
  const int rest = widx / NSPLIT;
  const int ti = rest % MAXT;
  const int nx = rest / MAXT;
  if (ti >= *ntile) return;
  const int tv = tiles[ti];
  const int e = tv >> 20;
  const int m0 = tv & 0xFFFFF;
  const int ce = cnt[e];
  const int oe = off[e];
  const int n0 = nx * 128;
  const int kbase = split * KCHUNK;

  const int tid = threadIdx.x;
  const int lane = tid & 63;
  const int w = tid >> 6;
  const int wr = (w >> 1) * 32;  // wave's M offset (64 split in 2)
  const int wc = (w & 1) * 64;   // wave's N offset (128 split in 2)
  const int fr = lane & 15;
  const int hi = lane >> 4;
  const int xr = (fr >> 1) & 3;

  // staging: thread t -> row t>>2 (64 rows), physical 16B slot t&3;
  // pre-swizzled global chunk c = (t&3) ^ ((row>>1)&3) = (t&3) ^ ((t>>3)&3)
  const int srow = tid >> 2;
  const int cch = (tid & 3) ^ ((tid >> 3) & 3);

  const __hip_bfloat16* ga;
  {
    int mr = m0 + srow;
    int src;
    if (GATHER_A) {
      src = list[oe + (mr < ce ? mr : 0)];
    } else {
      int p2 = oe + mr;
      src = p2 < NTOK ? p2 : NTOK - 1;
    }
    ga = A + (size_t)src * K_TOT + kbase + cch * 8;
  }
  const __hip_bfloat16* gb[2];
#pragma unroll
  for (int j = 0; j < 2; j++) {
    int nr = n0 + j * 64 + srow;
    gb[j] = BT + ((size_t)e * N + nr) * K_TOT + kbase + cch * 8;
  }

  f32x4 acc[2][4] = {};

#define STAGE(buf, kc)                                              \
  do {                                                              \
    GL16(ga + (kc), smem + (buf)*4096 + tid * 16);                  \
    GL16(gb[0] + (kc), smem + 8192 + (buf)*8192 + tid * 16);        \
    GL16(gb[1] + (kc), smem + 8192 + (buf)*8192 + 4096 + tid * 16); \
  } while (0)

  STAGE(0, 0);
#pragma unroll 1
  for (int t = 0; t < NT; ++t) {
    if (t + 1 < NT) {
      STAGE((t + 1) & 1, (t + 1) * 32);
      // wait only stage-t's 3 loads; keep the 3 just issued in flight
      asm volatile("s_waitcnt vmcnt(3)" ::: "memory");
    } else {
      asm volatile("s_waitcnt vmcnt(0)" ::: "memory");
    }
    __builtin_amdgcn_s_barrier();  // all waves' stage-t data in LDS
    {
      const char* bA = smem + (t & 1) * 4096;
      const char* bB = smem + 8192 + (t & 1) * 8192;
      bf16x8 fa[2], fb[4];
#pragma unroll
      for (int mf = 0; mf < 2; mf++) {
        const int row = wr + mf * 16 + fr;
        fa[mf] = *(const bf16x8*)(bA + row * 64 + ((hi ^ xr) * 16));
      }
#pragma unroll
      for (int nf = 0; nf < 4; nf++) {
        const int row = wc + nf * 16 + fr;
        fb[nf] = *(const bf16x8*)(bB + row * 64 + ((hi ^ xr) * 16));
      }
#pragma unroll
      for (int mf = 0; mf < 2; mf++)
#pragma unroll
        for (int nf = 0; nf < 4; nf++)
          acc[mf][nf] = __builtin_amdgcn_mfma_f32_16x16x32_bf16(fa[mf], fb[nf],
                                                                acc[mf][nf], 0, 0, 0);
    }
    __builtin_amdgcn_s_barrier();  // all waves done reading buf (t&1) -> reusable
  }
#undef STAGE

  // epilogue: C/D layout col = lane&15, row = (lane>>4)*4 + jj
#pragma unroll
  for (int mf = 0; mf < 2; mf++) {
#pragma unroll
    for (int jj = 0; jj < 4; jj++) {
      const int mloc = m0 + wr + mf * 16 + hi * 4 + jj;
      if (mloc >= ce) continue;
      if (RELU_BF16) {
        __hip_bfloat16* C = (__hip_bfloat16*)Cout;
        size_t row = (size_t)(oe + mloc) * N;
        const float* bi = bias + (size_t)e * N;
#pragma unroll
        for (int nf = 0; nf < 4; nf++) {
          int nn = n0 + wc + nf * 16 + fr;
          float v = acc[mf][nf][jj] + bi[nn];
          C[row + nn] = __float2bfloat16(v > 0.f ? v : 0.f);
        }
      } else {
        float* C = (float*)Cout;
        int tok = list[oe + mloc];
        size_t row = (size_t)tok * N;
        const float* bi = bias + (size_t)e * N;
#pragma unroll
        for (int nf = 0; nf < 4; nf++) {
          int nn = n0 + wc + nf * 16 + fr;
          float v = acc[mf][nf][jj] + (split == 0 ? bi[nn] : 0.f);
          if (ATOMIC_C)
            atomicAdd(&C[row + nn], v);
          else
            C[row + nn] = v;
        }
      }
    }
  }
}

// ---------------- fallback GEMM (round-1 kernel, used when ws too small) ----------
template <int K, int N, bool RELU_BF16, bool GATHER_A, bool SCATTER_C>
__global__ __launch_bounds__(256) void k_gemm(
    const __hip_bfloat16* __restrict__ A, const float* __restrict__ Bw,
    const float* __restrict__ bias, void* __restrict__ Cout,
    const int* __restrict__ cnt, const int* __restrict__ off,
    const int* __restrict__ list) {
  const int e = blockIdx.z;
  const int ce = cnt[e];
  const int m0 = blockIdx.y * 128;
  if (m0 >= ce) return;
  const int oe = off[e];
  const int n0 = blockIdx.x * 128;

  __shared__ __hip_bfloat16 Asm[128][32];
  __shared__ __hip_bfloat16 Bsm[128][32];

  const int tid = threadIdx.x;
  const int ra = tid >> 1;
  const int ha = (tid & 1) * 16;
  size_t arow;
  {
    int mr = m0 + ra;
    int src;
    if (GATHER_A) {
      src = (mr < ce) ? list[oe + mr] : list[oe];
    } else {
      int p = oe + mr;
      src = (p < NTOK) ? p : (NTOK - 1);
    }
    arow = (size_t)src * K;
  }
  const int rbk = tid >> 3;
  const int nb = (tid & 7) * 16;
  const float* bsrc0 = Bw + ((size_t)e * K + rbk) * N + n0 + nb;

  const int w = tid >> 6;
  const int lane = tid & 63;
  const int wr = (w >> 1) * 64;
  const int wc = (w & 1) * 64;
  const int fr = lane & 15;
  const int fk = (lane >> 4) * 8;

  f32x4 acc[4][4] = {};

  for (int k0 = 0; k0 < K; k0 += 32) {
    __syncthreads();
    {
      const __hip_bfloat16* s = A + arow + k0 + ha;
      int4 v0 = *(const int4*)(s);
      int4 v1 = *(const int4*)(s + 8);
      *(int4*)(&Asm[ra][ha]) = v0;
      *(int4*)(&Asm[ra][ha + 8]) = v1;
    }
    {
      const float* s = bsrc0 + (size_t)k0 * N;
      float4 q0 = *(const float4*)(s);
      float4 q1 = *(const float4*)(s + 4);
      float4 q2 = *(const float4*)(s + 8);
      float4 q3 = *(const float4*)(s + 12);
      __hip_bfloat16* dst = &Bsm[nb][0] + rbk;
      dst[0 * 32] = __float2bfloat16(q0.x);
      dst[1 * 32] = __float2bfloat16(q0.y);
      dst[2 * 32] = __float2bfloat16(q0.z);
      dst[3 * 32] = __float2bfloat16(q0.w);
      dst[4 * 32] = __float2bfloat16(q1.x);
      dst[5 * 32] = __float2bfloat16(q1.y);
      dst[6 * 32] = __float2bfloat16(q1.z);
      dst[7 * 32] = __float2bfloat16(q1.w);
      dst[8 * 32] = __float2bfloat16(q2.x);
      dst[9 * 32] = __float2bfloat16(q2.y);
      dst[10 * 32] = __float2bfloat16(q2.z);
      dst[11 * 32] = __float2bfloat16(q2.w);
      dst[12 * 32] = __float2bfloat16(q3.x);
      dst[13 * 32] = __float2bfloat16(q3.y);
      dst[14 * 32] = __float2bfloat16(q3.z);
      dst[15 * 32] = __float2bfloat16(q3.w);
    }
    __syncthreads();

    bf16x8 fa[4], fb[4];
#pragma unroll
    for (int mf = 0; mf < 4; mf++) fa[mf] = *(const bf16x8*)(&Asm[wr + mf * 16 + fr][fk]);
#pragma unroll
    for (int nf = 0; nf < 4; nf++) fb[nf] = *(const bf16x8*)(&Bsm[wc + nf * 16 + fr][fk]);
#pragma unroll
    for (int mf = 0; mf < 4; mf++)
#pragma unroll
      for (int nf = 0; nf < 4; nf++)
        acc[mf][nf] = __builtin_amdgcn_mfma_f32_16x16x32_bf16(fa[mf], fb[nf], acc[mf][nf], 0, 0, 0);
  }

#pragma unroll
  for (int mf = 0; mf < 4; mf++) {
#pragma unroll
    for (int j = 0; j < 4; j++) {
      const int mloc = m0 + wr + mf * 16 + (lane >> 4) * 4 + j;
      if (mloc >= ce) continue;
      if (RELU_BF16) {
        __hip_bfloat16* C = (__hip_bfloat16*)Cout;
        size_t row = (size_t)(oe + mloc) * N;
        const float* bi = bias + (size_t)e * N;
#pragma unroll
        for (int nf = 0; nf < 4; nf++) {
          int nn = n0 + wc + nf * 16 + fr;
          float v = acc[mf][nf][j] + bi[nn];
          C[row + nn] = __float2bfloat16(v > 0.f ? v : 0.f);
        }
      } else {
        float* C = (float*)Cout;
        int tok = SCATTER_C ? list[oe + mloc] : (oe + mloc);
        size_t row = (size_t)tok * N;
        const float* bi = bias + (size_t)e * N;
#pragma unroll
        for (int nf = 0; nf < 4; nf++) {
          int nn = n0 + wc + nf * 16 + fr;
          C[row + nn] = acc[mf][nf][j] + bi[nn];
        }
      }
    }
  }
}

// ws layout (bytes):
//   [0,32) cnt | [32,64) off | [64,96) spare | [96,100) ntile | [128,288) tiles[40]
//   [512,8704) eidx | [8704,16896) list
//   [65536,   +3145728)  xbf  bf16 [2048][768]
//   [4194304, +12582912) h    bf16 [2048][3072]
//   [20971520,+37748736) wT1 bf16 [8][3072][768]
//   [58720256,+37748736) wT2 bf16 [8][768][3072]   (REQ = 92 MiB)
extern "C" void kernel_launch(void* const* d_in, const int* in_sizes, int n_in,
                              void* d_out, int out_size, void* d_ws, size_t ws_size,
                              hipStream_t stream) {
  const float* x = (const float*)d_in[0];
  const float* rw = (const float*)d_in[1];
  const float* rb = (const float*)d_in[2];
  const float* w1 = (const float*)d_in[3];
  const float* b1 = (const float*)d_in[4];
  const float* w2 = (const float*)d_in[5];
  const float* b2 = (const float*)d_in[6];
  float* out = (float*)d_out;

  char* ws = (char*)d_ws;
  int* cnt = (int*)(ws + 0);
  int* off = (int*)(ws + 32);
  int* ntile = (int*)(ws + 96);
  int* tiles = (int*)(ws + 128);
  int* eidx = (int*)(ws + 512);
  int* list = (int*)(ws + 8704);
  __hip_bfloat16* xbf = (__hip_bfloat16*)(ws + 65536);
  __hip_bfloat16* h = (__hip_bfloat16*)(ws + 4194304);
  __hip_bfloat16* wT1 = (__hip_bfloat16*)(ws + 20971520);
  __hip_bfloat16* wT2 = (__hip_bfloat16*)(ws + 58720256);

  float* loss = out + (size_t)2 * 1024 * 768;
  const size_t REQ = 58720256ull + 37748736ull;  // 92 MiB

  (void)hipMemsetAsync(cnt, 0, 96, stream);
  (void)hipMemsetAsync(d_out, 0, (size_t)out_size * sizeof(float), stream);

  if (ws_size >= REQ) {
    const int TBLK = (DMODEL / 64) * (DFF / 64) * NEXP;  // 4608 64x64 transpose tiles
    // router + w1 transpose fused
    k_router_t1<<<512 + TBLK, 256, 0, stream>>>(x, rw, rb, xbf, eidx, cnt, w1, wT1);
    k_scanbuild<<<1, 256, 0, stream>>>(cnt, off, loss, tiles, ntile, eidx, list);
    // FFN1 GEMM (960 blocks) + fused w2 transpose (4608 blocks)
    k_gemm9<DMODEL, DMODEL, DFF, 1, true, true, false, DFF, DMODEL>
        <<<(DFF / 128) * MAXT + TBLK, 256, 0, stream>>>(
            xbf, wT1, b1, h, cnt, off, list, tiles, ntile, w2, wT2);
    // FFN2 GEMM: out += h @ w2T[e] + b2 (split-K=4, atomics into zeroed out)
    k_gemm9<DFF, DFF / 4, DMODEL, 4, false, false, true, 0, 64>
        <<<(DMODEL / 128) * MAXT * 4, 256, 0, stream>>>(
            h, wT2, b2, out, cnt, off, list, tiles, ntile, nullptr, nullptr);
  } else {
    // fallback: direct fp32-weight path (no transposes needed)
    k_router_t1<<<512, 256, 0, stream>>>(x, rw, rb, xbf, eidx, cnt, w1, nullptr);
    k_scanbuild<<<1, 256, 0, stream>>>(cnt, off, loss, tiles, ntile, eidx, list);
    k_gemm<DMODEL, DFF, true, true, false>
        <<<dim3(DFF / 128, 16, NEXP), 256, 0, stream>>>(xbf, w1, b1, h, cnt, off, list);
    k_gemm<DFF, DMODEL, false, false, true>
        <<<dim3(DMODEL / 128, 16, NEXP), 256, 0, stream>>>(h, w2, b2, out, cnt, off, list);
  }
}

// Round 15
// 126.389 us; speedup vs baseline: 1.1093x; 1.1093x over previous
//
#include <hip/hip_runtime.h>
#include <hip/hip_bf16.h>

#define NTOK 2048
#define DMODEL 768
#define DFF 3072
#define NEXP 8
#define MAXT 40  // max (expert,m0) tiles at M=64: 2048/64 + 7 = 39

typedef short bf16x8 __attribute__((ext_vector_type(8)));
typedef float f32x4 __attribute__((ext_vector_type(4)));

typedef __attribute__((address_space(1))) const char GCHAR;
typedef __attribute__((address_space(3))) char LCHAR;
#define GL16(g, l) __builtin_amdgcn_global_load_lds((GCHAR*)(g), (LCHAR*)(l), 16, 0, 0)

// ---- transpose one 64x64 tile: W[e][K][N] fp32 -> WT[e][N][K] bf16 (smem: 64x65 f32) ----
template <int K, int N>
__device__ void transpose_tile(const float* __restrict__ W, __hip_bfloat16* __restrict__ WT,
                               int e, int k0, int n0, float* T) {
  const int t = threadIdx.x;
  {
    const int kr = t >> 4;
    const int nc = (t & 15) * 4;
    const float* src = W + ((size_t)e * K + k0) * N + n0;
#pragma unroll
    for (int i = 0; i < 4; i++) {
      float4 v = *(const float4*)(src + (size_t)(kr + i * 16) * N + nc);
      T[(kr + i * 16) * 65 + nc + 0] = v.x;
      T[(kr + i * 16) * 65 + nc + 1] = v.y;
      T[(kr + i * 16) * 65 + nc + 2] = v.z;
      T[(kr + i * 16) * 65 + nc + 3] = v.w;
    }
  }
  __syncthreads();
  {
    const int n = t >> 2;
    const int kq = (t & 3) * 16;
    __align__(16) __hip_bfloat16 u[16];
#pragma unroll
    for (int j = 0; j < 16; j++) u[j] = __float2bfloat16(T[(kq + j) * 65 + n]);
    __hip_bfloat16* dst = WT + ((size_t)e * N + n0 + n) * K + k0 + kq;
    *(int4*)dst = *(const int4*)&u[0];
    *(int4*)(dst + 8) = *(const int4*)&u[8];
  }
}

// ---------------- router (blocks <512) fused with w1 transpose (blocks >=512) ----------
__global__ __launch_bounds__(256) void k_router_t1(
    const float* __restrict__ x, const float* __restrict__ rw,
    const float* __restrict__ rb, __hip_bfloat16* __restrict__ xbf,
    int* __restrict__ eidx, int* __restrict__ cnt,
    const float* __restrict__ w1, __hip_bfloat16* __restrict__ wT1) {
  __shared__ float T[64 * 65];
  if (blockIdx.x >= 512) {
    int tb = blockIdx.x - 512;
    int n_i = tb % (DFF / 64);
    int k_i = (tb / (DFF / 64)) % (DMODEL / 64);
    int e = tb / ((DFF / 64) * (DMODEL / 64));
    transpose_tile<DMODEL, DFF>(w1, wT1, e, k_i * 64, n_i * 64, T);
    return;
  }
  int tok = (blockIdx.x * blockDim.x + threadIdx.x) >> 6;
  int lane = threadIdx.x & 63;
  if (tok >= NTOK) return;
  const float* xr = x + (size_t)tok * DMODEL;
  double acc[NEXP];
#pragma unroll
  for (int e = 0; e < NEXP; e++) acc[e] = 0.0;
  for (int d0 = 0; d0 < DMODEL; d0 += 64) {
    float v = xr[d0 + lane];
    xbf[(size_t)tok * DMODEL + d0 + lane] = __float2bfloat16(v);
    const float* wrow = rw + (size_t)(d0 + lane) * NEXP;
#pragma unroll
    for (int e = 0; e < NEXP; e++) acc[e] += (double)v * (double)wrow[e];
  }
#pragma unroll
  for (int e = 0; e < NEXP; e++) {
    double a = acc[e];
#pragma unroll
    for (int s = 32; s > 0; s >>= 1) a += __shfl_xor(a, s);
    acc[e] = a;
  }
  if (lane == 0) {
    int best = 0;
    double bv = acc[0] + (double)rb[0];
#pragma unroll
    for (int e = 1; e < NEXP; e++) {
      double v = acc[e] + (double)rb[e];
      if (v > bv) { bv = v; best = e; }  // strict > keeps first max (jnp.argmax)
    }
    eidx[tok] = best;
    atomicAdd(&cnt[best], 1);
  }
}

// ------- fused: prefix scan + loss + tile list (M=64) + packed token-list build -------
__global__ __launch_bounds__(256) void k_scanbuild(
    const int* __restrict__ cnt, int* __restrict__ off, float* __restrict__ loss,
    int* __restrict__ tiles, int* __restrict__ ntile,
    const int* __restrict__ eidx, int* __restrict__ list) {
  __shared__ int s_cur[NEXP];
  if (threadIdx.x == 0) {
    int s = 0;
    float l = 0.f;
    int nt = 0;
    for (int e = 0; e < NEXP; e++) {
      off[e] = s;
      s_cur[e] = s;
      for (int m = 0; m < cnt[e]; m += 64) tiles[nt++] = (e << 20) | m;
      s += cnt[e];
      float u = (float)cnt[e] / (float)NTOK - 1.0f / (float)NEXP;
      l += u * u;
    }
    *ntile = nt;
    *loss = l / (float)NEXP;
  }
  __syncthreads();
  for (int t = threadIdx.x; t < NTOK; t += 256) {
    int e = eidx[t];
    int p = atomicAdd(&s_cur[e], 1);
    list[p] = t;
  }
}

// ---- grouped GEMM (r9-best): 64Mx128N tile, BK=32, dbuf 24KB LDS (6 blocks/CU),
// counted vmcnt(3) + raw barriers, gload_lds both operands, XCD swizzle,
// fused 64x64 w2-transpose blocks. Chunk swizzle: phys 16B chunk = log ^ ((row>>1)&3).
template <int K_TOT, int KCHUNK, int N, int NSPLIT, bool RELU_BF16, bool GATHER_A,
          int TK, int TN>
__global__ __launch_bounds__(256, 6) void k_gemm9(
    const __hip_bfloat16* __restrict__ A, const __hip_bfloat16* __restrict__ BT,
    const float* __restrict__ bias, void* __restrict__ Cout,
    const int* __restrict__ cnt, const int* __restrict__ off,
    const int* __restrict__ list, const int* __restrict__ tiles,
    const int* __restrict__ ntile, const float* __restrict__ Tsrc,
    __hip_bfloat16* __restrict__ Tdst) {
  constexpr int NX = N / 128;
  constexpr int W = NX * MAXT * NSPLIT;
  constexpr int NT = KCHUNK / 32;
  __shared__ __align__(16) char smem[24576];  // A dbuf 2x4KB @0 | B dbuf 2x8KB @8192
                                              // transpose branch: 64x65 f32 = 16.9KB

  if constexpr (TK > 0) {
    if (blockIdx.x >= W) {
      int tb = blockIdx.x - W;
      int n_i = tb % (TN / 64);
      int k_i = (tb / (TN / 64)) % (TK / 64);
      int e = tb / ((TN / 64) * (TK / 64));
      transpose_tile<TK, TN>(Tsrc, Tdst, e, k_i * 64, n_i * 64, (float*)smem);
      return;
    }
  }

  // bijective XCD swizzle; decompose split-fastest, then tile, then n-tile
  int b = blockIdx.x;
  constexpr int q = W / 8, r = W % 8;
  const int xcd = b & 7, ii = b >> 3;
  const int widx = (xcd < r ? xcd * (q + 1) : r * (q + 1) + (xcd - r) * q) + ii;
  const int split = widx % NSPLIT;
  const int rest = widx / NSPLIT;
  const int ti = rest % MAXT;
  const int nx = rest / MAXT;
  if (ti >= *ntile) return;
  const int tv = tiles[ti];
  const int e = tv >> 20;
  const int m0 = tv & 0xFFFFF;
  const int ce = cnt[e];
  const int oe = off[e];
  const int n0 = nx * 128;
  const int kbase = split * KCHUNK;

  const int tid = threadIdx.x;
  const int lane = tid & 63;
  const int w = tid >> 6;
  const int wr = (w >> 1) * 32;  // wave's M offset (64 split in 2)
  const int wc = (w & 1) * 64;   // wave's N offset (128 split in 2)
  const int fr = lane & 15;
  const int hi = lane >> 4;
  const int xr = (fr >> 1) & 3;

  // staging: thread t -> row t>>2 (64 rows), physical 16B slot t&3;
  // pre-swizzled global chunk c = (t&3) ^ ((row>>1)&3) = (t&3) ^ ((t>>3)&3)
  const int srow = tid >> 2;
  const int cch = (tid & 3) ^ ((tid >> 3) & 3);

  const __hip_bfloat16* ga;
  {
    int mr = m0 + srow;
    int src;
    if (GATHER_A) {
      src = list[oe + (mr < ce ? mr : 0)];
    } else {
      int p2 = oe + mr;
      src = p2 < NTOK ? p2 : NTOK - 1;
    }
    ga = A + (size_t)src * K_TOT + kbase + cch * 8;
  }
  const __hip_bfloat16* gb[2];
#pragma unroll
  for (int j = 0; j < 2; j++) {
    int nr = n0 + j * 64 + srow;
    gb[j] = BT + ((size_t)e * N + nr) * K_TOT + kbase + cch * 8;
  }

  f32x4 acc[2][4] = {};

#define STAGE(buf, kc)                                              \
  do {                                                              \
    GL16(ga + (kc), smem + (buf)*4096 + tid * 16);                  \
    GL16(gb[0] + (kc), smem + 8192 + (buf)*8192 + tid * 16);        \
    GL16(gb[1] + (kc), smem + 8192 + (buf)*8192 + 4096 + tid * 16); \
  } while (0)

  STAGE(0, 0);
#pragma unroll 1
  for (int t = 0; t < NT; ++t) {
    if (t + 1 < NT) {
      STAGE((t + 1) & 1, (t + 1) * 32);
      // wait only stage-t's 3 loads; keep the 3 just issued in flight
      asm volatile("s_waitcnt vmcnt(3)" ::: "memory");
    } else {
      asm volatile("s_waitcnt vmcnt(0)" ::: "memory");
    }
    __builtin_amdgcn_s_barrier();  // all waves' stage-t data in LDS
    {
      const char* bA = smem + (t & 1) * 4096;
      const char* bB = smem + 8192 + (t & 1) * 8192;
      bf16x8 fa[2], fb[4];
#pragma unroll
      for (int mf = 0; mf < 2; mf++) {
        const int row = wr + mf * 16 + fr;
        fa[mf] = *(const bf16x8*)(bA + row * 64 + ((hi ^ xr) * 16));
      }
#pragma unroll
      for (int nf = 0; nf < 4; nf++) {
        const int row = wc + nf * 16 + fr;
        fb[nf] = *(const bf16x8*)(bB + row * 64 + ((hi ^ xr) * 16));
      }
#pragma unroll
      for (int mf = 0; mf < 2; mf++)
#pragma unroll
        for (int nf = 0; nf < 4; nf++)
          acc[mf][nf] = __builtin_amdgcn_mfma_f32_16x16x32_bf16(fa[mf], fb[nf],
                                                                acc[mf][nf], 0, 0, 0);
    }
    __builtin_amdgcn_s_barrier();  // all waves done reading buf (t&1) -> reusable
  }
#undef STAGE

  // epilogue: C/D layout col = lane&15, row = (lane>>4)*4 + jj
#pragma unroll
  for (int mf = 0; mf < 2; mf++) {
#pragma unroll
    for (int jj = 0; jj < 4; jj++) {
      const int mloc = m0 + wr + mf * 16 + hi * 4 + jj;
      if (mloc >= ce) continue;
      if (RELU_BF16) {
        __hip_bfloat16* C = (__hip_bfloat16*)Cout;
        size_t row = (size_t)(oe + mloc) * N;
        const float* bi = bias + (size_t)e * N;
#pragma unroll
        for (int nf = 0; nf < 4; nf++) {
          int nn = n0 + wc + nf * 16 + fr;
          float v = acc[mf][nf][jj] + bi[nn];
          C[row + nn] = __float2bfloat16(v > 0.f ? v : 0.f);
        }
      } else {  // partial store: bias added in k_reduce
        float* C = (float*)Cout;
        int tok = list[oe + mloc];
        size_t row = ((size_t)split * NTOK + tok) * N;
#pragma unroll
        for (int nf = 0; nf < 4; nf++) {
          int nn = n0 + wc + nf * 16 + fr;
          C[row + nn] = acc[mf][nf][jj];
        }
      }
    }
  }
}

// ---- reduce 4 split-K partials + per-expert bias -> out ----
__global__ __launch_bounds__(256) void k_reduce(const float* __restrict__ p,
                                                const float* __restrict__ b2,
                                                const int* __restrict__ eidx,
                                                float* __restrict__ out) {
  const int idx = blockIdx.x * 256 + threadIdx.x;
  const int base = idx * 4;
  const int tok = base / DMODEL;
  const int n = base - tok * DMODEL;
  const int e = eidx[tok];
  float4 a = *(const float4*)(p + (size_t)0 * NTOK * DMODEL + base);
  float4 c = *(const float4*)(p + (size_t)1 * NTOK * DMODEL + base);
  float4 d = *(const float4*)(p + (size_t)2 * NTOK * DMODEL + base);
  float4 g = *(const float4*)(p + (size_t)3 * NTOK * DMODEL + base);
  float4 bb = *(const float4*)(b2 + (size_t)e * DMODEL + n);
  float4 o;
  o.x = a.x + c.x + d.x + g.x + bb.x;
  o.y = a.y + c.y + d.y + g.y + bb.y;
  o.z = a.z + c.z + d.z + g.z + bb.z;
  o.w = a.w + c.w + d.w + g.w + bb.w;
  *(float4*)(out + base) = o;
}

// ---------------- fallback GEMM (round-1 kernel, used when ws too small) ----------
template <int K, int N, bool RELU_BF16, bool GATHER_A, bool SCATTER_C>
__global__ __launch_bounds__(256) void k_gemm(
    const __hip_bfloat16* __restrict__ A, const float* __restrict__ Bw,
    const float* __restrict__ bias, void* __restrict__ Cout,
    const int* __restrict__ cnt, const int* __restrict__ off,
    const int* __restrict__ list) {
  const int e = blockIdx.z;
  const int ce = cnt[e];
  const int m0 = blockIdx.y * 128;
  if (m0 >= ce) return;
  const int oe = off[e];
  const int n0 = blockIdx.x * 128;

  __shared__ __hip_bfloat16 Asm[128][32];
  __shared__ __hip_bfloat16 Bsm[128][32];

  const int tid = threadIdx.x;
  const int ra = tid >> 1;
  const int ha = (tid & 1) * 16;
  size_t arow;
  {
    int mr = m0 + ra;
    int src;
    if (GATHER_A) {
      src = (mr < ce) ? list[oe + mr] : list[oe];
    } else {
      int p = oe + mr;
      src = (p < NTOK) ? p : (NTOK - 1);
    }
    arow = (size_t)src * K;
  }
  const int rbk = tid >> 3;
  const int nb = (tid & 7) * 16;
  const float* bsrc0 = Bw + ((size_t)e * K + rbk) * N + n0 + nb;

  const int w = tid >> 6;
  const int lane = tid & 63;
  const int wr = (w >> 1) * 64;
  const int wc = (w & 1) * 64;
  const int fr = lane & 15;
  const int fk = (lane >> 4) * 8;

  f32x4 acc[4][4] = {};

  for (int k0 = 0; k0 < K; k0 += 32) {
    __syncthreads();
    {
      const __hip_bfloat16* s = A + arow + k0 + ha;
      int4 v0 = *(const int4*)(s);
      int4 v1 = *(const int4*)(s + 8);
      *(int4*)(&Asm[ra][ha]) = v0;
      *(int4*)(&Asm[ra][ha + 8]) = v1;
    }
    {
      const float* s = bsrc0 + (size_t)k0 * N;
      float4 q0 = *(const float4*)(s);
      float4 q1 = *(const float4*)(s + 4);
      float4 q2 = *(const float4*)(s + 8);
      float4 q3 = *(const float4*)(s + 12);
      __hip_bfloat16* dst = &Bsm[nb][0] + rbk;
      dst[0 * 32] = __float2bfloat16(q0.x);
      dst[1 * 32] = __float2bfloat16(q0.y);
      dst[2 * 32] = __float2bfloat16(q0.z);
      dst[3 * 32] = __float2bfloat16(q0.w);
      dst[4 * 32] = __float2bfloat16(q1.x);
      dst[5 * 32] = __float2bfloat16(q1.y);
      dst[6 * 32] = __float2bfloat16(q1.z);
      dst[7 * 32] = __float2bfloat16(q1.w);
      dst[8 * 32] = __float2bfloat16(q2.x);
      dst[9 * 32] = __float2bfloat16(q2.y);
      dst[10 * 32] = __float2bfloat16(q2.z);
      dst[11 * 32] = __float2bfloat16(q2.w);
      dst[12 * 32] = __float2bfloat16(q3.x);
      dst[13 * 32] = __float2bfloat16(q3.y);
      dst[14 * 32] = __float2bfloat16(q3.z);
      dst[15 * 32] = __float2bfloat16(q3.w);
    }
    __syncthreads();

    bf16x8 fa[4], fb[4];
#pragma unroll
    for (int mf = 0; mf < 4; mf++) fa[mf] = *(const bf16x8*)(&Asm[wr + mf * 16 + fr][fk]);
#pragma unroll
    for (int nf = 0; nf < 4; nf++) fb[nf] = *(const bf16x8*)(&Bsm[wc + nf * 16 + fr][fk]);
#pragma unroll
    for (int mf = 0; mf < 4; mf++)
#pragma unroll
      for (int nf = 0; nf < 4; nf++)
        acc[mf][nf] = __builtin_amdgcn_mfma_f32_16x16x32_bf16(fa[mf], fb[nf], acc[mf][nf], 0, 0, 0);
  }

#pragma unroll
  for (int mf = 0; mf < 4; mf++) {
#pragma unroll
    for (int j = 0; j < 4; j++) {
      const int mloc = m0 + wr + mf * 16 + (lane >> 4) * 4 + j;
      if (mloc >= ce) continue;
      if (RELU_BF16) {
        __hip_bfloat16* C = (__hip_bfloat16*)Cout;
        size_t row = (size_t)(oe + mloc) * N;
        const float* bi = bias + (size_t)e * N;
#pragma unroll
        for (int nf = 0; nf < 4; nf++) {
          int nn = n0 + wc + nf * 16 + fr;
          float v = acc[mf][nf][j] + bi[nn];
          C[row + nn] = __float2bfloat16(v > 0.f ? v : 0.f);
        }
      } else {
        float* C = (float*)Cout;
        int tok = SCATTER_C ? list[oe + mloc] : (oe + mloc);
        size_t row = (size_t)tok * N;
        const float* bi = bias + (size_t)e * N;
#pragma unroll
        for (int nf = 0; nf < 4; nf++) {
          int nn = n0 + wc + nf * 16 + fr;
          C[row + nn] = acc[mf][nf][j] + bi[nn];
        }
      }
    }
  }
}

// ws layout (bytes):
//   [0,32) cnt | [32,64) off | [64,96) spare | [96,100) ntile | [128,288) tiles[40]
//   [512,8704) eidx | [8704,16896) list
//   [65536,   +3145728)  xbf  bf16 [2048][768]
//   [4194304, +12582912) h    bf16 [2048][3072]
//   [20971520,+37748736) wT1 bf16 [8][3072][768]  (aliased by partials [4][2048][768]
//                                                  fp32, 25.2MB -- time-disjoint)
//   [58720256,+37748736) wT2 bf16 [8][768][3072]   (REQ = 92 MiB)
extern "C" void kernel_launch(void* const* d_in, const int* in_sizes, int n_in,
                              void* d_out, int out_size, void* d_ws, size_t ws_size,
                              hipStream_t stream) {
  const float* x = (const float*)d_in[0];
  const float* rw = (const float*)d_in[1];
  const float* rb = (const float*)d_in[2];
  const float* w1 = (const float*)d_in[3];
  const float* b1 = (const float*)d_in[4];
  const float* w2 = (const float*)d_in[5];
  const float* b2 = (const float*)d_in[6];
  float* out = (float*)d_out;

  char* ws = (char*)d_ws;
  int* cnt = (int*)(ws + 0);
  int* off = (int*)(ws + 32);
  int* ntile = (int*)(ws + 96);
  int* tiles = (int*)(ws + 128);
  int* eidx = (int*)(ws + 512);
  int* list = (int*)(ws + 8704);
  __hip_bfloat16* xbf = (__hip_bfloat16*)(ws + 65536);
  __hip_bfloat16* h = (__hip_bfloat16*)(ws + 4194304);
  __hip_bfloat16* wT1 = (__hip_bfloat16*)(ws + 20971520);
  float* part = (float*)(ws + 20971520);  // aliases wT1 (dead by FFN2 time)
  __hip_bfloat16* wT2 = (__hip_bfloat16*)(ws + 58720256);

  float* loss = out + (size_t)2 * 1024 * 768;
  const size_t REQ = 58720256ull + 37748736ull;  // 92 MiB

  (void)hipMemsetAsync(cnt, 0, 96, stream);
  if (ws_size < REQ)
    (void)hipMemsetAsync(d_out, 0, (size_t)out_size * sizeof(float), stream);

  if (ws_size >= REQ) {
    const int TBLK = (DMODEL / 64) * (DFF / 64) * NEXP;  // 4608 64x64 transpose tiles
    // router + w1 transpose fused
    k_router_t1<<<512 + TBLK, 256, 0, stream>>>(x, rw, rb, xbf, eidx, cnt, w1, wT1);
    k_scanbuild<<<1, 256, 0, stream>>>(cnt, off, loss, tiles, ntile, eidx, list);
    // FFN1 GEMM (960 blocks) + fused w2 transpose (4608 blocks)
    k_gemm9<DMODEL, DMODEL, DFF, 1, true, true, DFF, DMODEL>
        <<<(DFF / 128) * MAXT + TBLK, 256, 0, stream>>>(
            xbf, wT1, b1, h, cnt, off, list, tiles, ntile, w2, wT2);
    // FFN2 GEMM: partials[split] = h @ w2T[e], split-K=4 (960 blocks)
    k_gemm9<DFF, DFF / 4, DMODEL, 4, false, false, 0, 64>
        <<<(DMODEL / 128) * MAXT * 4, 256, 0, stream>>>(
            h, wT2, nullptr, part, cnt, off, list, tiles, ntile, nullptr, nullptr);
    k_reduce<<<(NTOK * DMODEL) / 1024, 256, 0, stream>>>(part, b2, eidx, out);
  } else {
    // fallback: direct fp32-weight path (no transposes needed)
    k_router_t1<<<512, 256, 0, stream>>>(x, rw, rb, xbf, eidx, cnt, w1, nullptr);
    k_scanbuild<<<1, 256, 0, stream>>>(cnt, off, loss, tiles, ntile, eidx, list);
    k_gemm<DMODEL, DFF, true, true, false>
        <<<dim3(DFF / 128, 16, NEXP), 256, 0, stream>>>(xbf, w1, b1, h, cnt, off, list);
    k_gemm<DFF, DMODEL, false, false, true>
        <<<dim3(DMODEL / 128, 16, NEXP), 256, 0, stream>>>(h, w2, b2, out, cnt, off, list);
  }
}